// Round 1
// baseline (55519.189 us; speedup 1.0000x reference)
//
#include <hip/hip_runtime.h>
#include <math.h>

// ===== jax threefry mode: 1 = partitionable (jax >= 0.4.36 default), 0 = original =====
#define JAX_PARTITIONABLE 1

// ---- model dims: NL=6 D=256 FF=1024 V=1024 S=48 BS=64 H=8 DH=32 ----

// ---- workspace layout (float offsets) ----
static constexpr int PE_OFF  = 0;                        // 49*256
static constexpr int X_OFF   = PE_OFF + 49*256;          // 3072*256
static constexpr int MEM_OFF = X_OFF + 3072*256;         // 3072*256
static constexpr int CK_OFF  = MEM_OFF + 3072*256;       // 6*3072*256
static constexpr int CV_OFF  = CK_OFF + 6*3072*256;
static constexpr int SK_OFF  = CV_OFF + 6*3072*256;
static constexpr int SV_OFF  = SK_OFF + 6*3072*256;
static constexpr int Y0_OFF  = SV_OFF + 6*3072*256;      // 64*256
static constexpr int YIN_OFF = Y0_OFF + 64*256;
static constexpr int Y1B_OFF = YIN_OFF + 64*256;
static constexpr int Y2B_OFF = Y1B_OFF + 64*256;
static constexpr int PO1_OFF = Y2B_OFF + 64*256;         // 8*64*256
static constexpr int PO2_OFF = PO1_OFF + 8*64*256;
static constexpr int FP_OFF  = PO2_OFF + 8*64*256;
static constexpr int WS_FLOATS = FP_OFF + 8*64*256;      // ~20.9M floats (~84 MB)
// encoder temporaries alias the (decode-only) self KV cache region:
static constexpr int QKV_OFF  = SK_OFF;                  // 3072*768
static constexpr int AO_OFF   = QKV_OFF + 3072*768;      // 3072*256
static constexpr int RES1_OFF = AO_OFF + 3072*256;       // 3072*256
static constexpr int X1_OFF   = RES1_OFF + 3072*256;     // 3072*256 (ends exactly at SV_OFF)
static constexpr int HB_OFF   = SV_OFF;                  // 3072*1024
static constexpr int RES2_OFF = HB_OFF + 3072*1024;      // 3072*256

struct GParams {
  const int   *xc, *xct;
  const float *sos, *emb, *hw, *hb;
  const float *ewqkv, *ebqkv, *ewo, *ebo, *ew1, *eb1, *ew2, *eb2, *elnw, *elnb;
  const float *swqkv, *sbqkv, *swo, *sbo;
  const float *cwqkv, *cbqkv, *cwo, *cbo;
  const float *dw1, *db1, *dw2, *db2, *dlnw, *dlnb, *lnfw, *lnfb;
  float *out;
  float *ws;
};

// ---- device-global barrier state (zero-init at load; generation counters survive replays) ----
__device__ unsigned g_cntA = 0, g_genA = 0, g_cntB = 0, g_genB = 0;

static __device__ __forceinline__ void gbar(unsigned* cnt, unsigned* gen, unsigned nb) {
  __syncthreads();
  if (threadIdx.x == 0) {
    __threadfence();
    unsigned g = __hip_atomic_load(gen, __ATOMIC_RELAXED, __HIP_MEMORY_SCOPE_AGENT);
    unsigned prev = __hip_atomic_fetch_add(cnt, 1u, __ATOMIC_ACQ_REL, __HIP_MEMORY_SCOPE_AGENT);
    if (prev == nb - 1u) {
      __hip_atomic_store(cnt, 0u, __ATOMIC_RELAXED, __HIP_MEMORY_SCOPE_AGENT);
      __threadfence();
      __hip_atomic_store(gen, g + 1u, __ATOMIC_RELEASE, __HIP_MEMORY_SCOPE_AGENT);
    } else {
      while (__hip_atomic_load(gen, __ATOMIC_ACQUIRE, __HIP_MEMORY_SCOPE_AGENT) == g)
        __builtin_amdgcn_s_sleep(1);
      __threadfence();
    }
  }
  __syncthreads();
}

// ---- threefry2x32 (exact jax rotation/key schedule) ----
static __device__ __forceinline__ void tf2x32(unsigned k0, unsigned k1, unsigned& x0, unsigned& x1) {
  unsigned ks2 = k0 ^ k1 ^ 0x1BD11BDAu;
  x0 += k0; x1 += k1;
#define TF_R(r) { x0 += x1; x1 = (x1 << r) | (x1 >> (32 - r)); x1 ^= x0; }
  TF_R(13) TF_R(15) TF_R(26) TF_R(6)   x0 += k1;  x1 += ks2 + 1u;
  TF_R(17) TF_R(29) TF_R(16) TF_R(24)  x0 += ks2; x1 += k0  + 2u;
  TF_R(13) TF_R(15) TF_R(26) TF_R(6)   x0 += k0;  x1 += k1  + 3u;
  TF_R(17) TF_R(29) TF_R(16) TF_R(24)  x0 += k1;  x1 += ks2 + 4u;
  TF_R(13) TF_R(15) TF_R(26) TF_R(6)   x0 += ks2; x1 += k0  + 5u;
#undef TF_R
}

static __device__ __forceinline__ void step_key(int i, unsigned& k0, unsigned& k1) {
#if JAX_PARTITIONABLE
  unsigned x0 = 0u, x1 = (unsigned)i;
  tf2x32(0u, 42u, x0, x1);
  k0 = x0; k1 = x1;
#else
  unsigned w[2];
  for (int wi = 0; wi < 2; wi++) {
    unsigned o = (unsigned)(2*i + wi), x0, x1;
    if (o < 48u) { x0 = o; x1 = 48u + o; tf2x32(0u, 42u, x0, x1); w[wi] = x0; }
    else         { x0 = o - 48u; x1 = o; tf2x32(0u, 42u, x0, x1); w[wi] = x1; }
  }
  k0 = w[0]; k1 = w[1];
#endif
}

static __device__ __forceinline__ unsigned gumbel_bits(unsigned k0, unsigned k1, int b, int v) {
#if JAX_PARTITIONABLE
  unsigned x0 = 0u, x1 = (unsigned)(b*1024 + v);
  tf2x32(k0, k1, x0, x1);
  return x0 ^ x1;
#else
  unsigned jj = (unsigned)((b & 31)*1024 + v);
  unsigned x0 = jj, x1 = 32768u + jj;
  tf2x32(k0, k1, x0, x1);
  return (b < 32) ? x0 : x1;
#endif
}

// ---- positional encoding element (matches f32 jax trace) ----
static __device__ __forceinline__ float pe_val(int p, int c) {
  const float KC = (float)(-9.210340371976184 / 256.0); // -log(10000)/256 in f64 then f32
  int j = c >> 1;
  float dv = expf((float)(2*j) * KC);
  float a = (float)p * dv;
  return (c & 1) ? cosf(a) : sinf(a);
}

// ---- per-wave LayerNorm of a 256-float LDS row (two-pass, matches reference) ----
static __device__ __forceinline__ void wave_ln_row(float* row, const float* lw, const float* lb) {
  const int lane = threadIdx.x & 63;
  float x0 = row[lane], x1 = row[lane+64], x2 = row[lane+128], x3 = row[lane+192];
  float s = (x0 + x1) + (x2 + x3);
#pragma unroll
  for (int m = 1; m < 64; m <<= 1) s += __shfl_xor(s, m);
  float mean = s * 0.00390625f;
  float d0 = x0-mean, d1 = x1-mean, d2 = x2-mean, d3 = x3-mean;
  float q = (d0*d0 + d1*d1) + (d2*d2 + d3*d3);
#pragma unroll
  for (int m = 1; m < 64; m <<= 1) q += __shfl_xor(q, m);
  float rs = 1.0f / sqrtf(q * 0.00390625f + 1e-5f);
  row[lane]     = d0*rs*lw[lane]     + lb[lane];
  row[lane+64]  = d1*rs*lw[lane+64]  + lb[lane+64];
  row[lane+128] = d2*rs*lw[lane+128] + lb[lane+128];
  row[lane+192] = d3*rs*lw[lane+192] + lb[lane+192];
}

// ---- reconstruct nr rows = LN(base + bias + sum of 8 partials) into LDS ----
static __device__ void build_rows_ln(const float* base, const float* bias, const float* part,
                                     const float* lw, const float* lb,
                                     int b0, int nr, float* rows) {
  const int t = threadIdx.x;
  for (int r = 0; r < nr; r++) {
    int b = b0 + r;
    float v = base[b*256 + t] + bias[t];
    if (part) {
#pragma unroll
      for (int u = 0; u < 8; u++) v += part[(u*64 + b)*256 + t];
    }
    rows[r*256 + t] = v;
  }
  __syncthreads();
  const int wv = t >> 6;
  for (int r = wv; r < nr; r += 4) wave_ln_row(rows + r*256, lw, lb);
  __syncthreads();
}

// ---- generic tiled GEMM stage: out[R][C] = A[R][K] @ W[C][K]^T (+bias)(relu)(+res) ----
static __device__ void gemm_stage(const float* __restrict__ A, const float* __restrict__ W,
                                  const float* __restrict__ bias, const float* __restrict__ res,
                                  float* __restrict__ out, int R, int C, int K, int relu,
                                  float* sA) {
  const int t = threadIdx.x;
  const int lane = t & 63, wv = t >> 6;
  const int ntc = C >> 6;
  const int ntiles = (R >> 5) * ntc;
  for (int tile = blockIdx.x; tile < ntiles; tile += gridDim.x) {
    const int tr = tile / ntc, tc = tile - tr*ntc;
    const int r0 = tr << 5;
    const int c  = (tc << 6) + lane;
    float acc[8] = {0,0,0,0,0,0,0,0};
    for (int kc = 0; kc < K; kc += 256) {
      __syncthreads();
#pragma unroll
      for (int u = 0; u < 8; u++) {
        int idx = u*256 + t;
        int rr = idx >> 6, cc = idx & 63;
        ((float4*)sA)[idx] = *(const float4*)(A + (r0+rr)*K + kc + cc*4);
      }
      __syncthreads();
      const float* wr = W + c*K + kc;
      for (int k = 0; k < 256; k += 4) {
        float4 w4 = *(const float4*)(wr + k);
#pragma unroll
        for (int r = 0; r < 8; r++) {
          float4 a4 = *(const float4*)(sA + (wv*8 + r)*256 + k);
          acc[r] += a4.x*w4.x; acc[r] += a4.y*w4.y; acc[r] += a4.z*w4.z; acc[r] += a4.w*w4.w;
        }
      }
    }
    float bb = bias ? bias[c] : 0.0f;
#pragma unroll
    for (int r = 0; r < 8; r++) {
      int row = r0 + wv*8 + r;
      float v = acc[r] + bb;
      if (relu) v = fmaxf(v, 0.0f);
      if (res)  v += res[row*C + c];
      out[row*C + c] = v;
    }
  }
}

// ---- standalone LN stage (encoder): out = LN(in), R rows of 256 ----
static __device__ void ln_stage(const float* in, const float* lw, const float* lb,
                                float* out, int R) {
  const int lane = threadIdx.x & 63;
  int gw = blockIdx.x*4 + (threadIdx.x >> 6);
  for (int row = gw; row < R; row += gridDim.x*4) {
    const float* ir = in + row*256;
    float x0 = ir[lane], x1 = ir[lane+64], x2 = ir[lane+128], x3 = ir[lane+192];
    float s = (x0 + x1) + (x2 + x3);
#pragma unroll
    for (int m = 1; m < 64; m <<= 1) s += __shfl_xor(s, m);
    float mean = s * 0.00390625f;
    float d0 = x0-mean, d1 = x1-mean, d2 = x2-mean, d3 = x3-mean;
    float q = (d0*d0 + d1*d1) + (d2*d2 + d3*d3);
#pragma unroll
    for (int m = 1; m < 64; m <<= 1) q += __shfl_xor(q, m);
    float rs = 1.0f / sqrtf(q * 0.00390625f + 1e-5f);
    float* orow = out + row*256;
    orow[lane]     = d0*rs*lw[lane]     + lb[lane];
    orow[lane+64]  = d1*rs*lw[lane+64]  + lb[lane+64];
    orow[lane+128] = d2*rs*lw[lane+128] + lb[lane+128];
    orow[lane+192] = d3*rs*lw[lane+192] + lb[lane+192];
  }
}

// ---- attention core: 8 query rows (q in LDS qd[8][32]) vs nk keys; softmax matches ref ----
static __device__ void attn_core(const float* qd, const float* kb, const float* vb,
                                 int krstride, int kstride, int nk,
                                 float* sc, float* red, float* ao) {
  const int t = threadIdx.x;
  const int r = t >> 5, p0 = t & 31;
#pragma unroll
  for (int pass = 0; pass < 2; pass++) {
    int p = pass*32 + p0;
    if (p < nk) {
      const float4* k4 = (const float4*)(kb + r*krstride + p*kstride);
      const float4* q4 = (const float4*)(qd + r*32);
      float a = 0.0f;
#pragma unroll
      for (int d4 = 0; d4 < 8; d4++) {
        float4 kv = k4[d4], qv = q4[d4];
        a += qv.x*kv.x; a += qv.y*kv.y; a += qv.z*kv.z; a += qv.w*kv.w;
      }
      sc[r*48 + p] = a * 0.17677669529663687f; // 1/sqrt(32), scale applied to the score
    }
  }
  __syncthreads();
  if (t < 8) {
    float m = sc[t*48];
    for (int p = 1; p < nk; p++) m = fmaxf(m, sc[t*48 + p]);
    red[t] = m;
  }
  __syncthreads();
#pragma unroll
  for (int pass = 0; pass < 2; pass++) {
    int p = pass*32 + p0;
    if (p < nk) sc[r*48 + p] = expf(sc[r*48 + p] - red[r]);
  }
  __syncthreads();
  if (t < 8) {
    float s = 0.0f;
    for (int p = 0; p < nk; p++) s += sc[t*48 + p];
    red[8 + t] = s;
  }
  __syncthreads();
#pragma unroll
  for (int pass = 0; pass < 2; pass++) {
    int p = pass*32 + p0;
    if (p < nk) sc[r*48 + p] = sc[r*48 + p] / red[8 + r];   // probs via division (ref order)
  }
  __syncthreads();
  {
    const int d2 = t & 31;
    const float* vr = vb + r*krstride + d2;
    float a = 0.0f;
    for (int p = 0; p < nk; p++) a += sc[r*48 + p] * vr[p*kstride];
    ao[r*32 + d2] = a;
  }
  __syncthreads();
}

// ---- encoder attention stage: full (no mask), per (b,h) pair ----
static __device__ void enc_attn_stage(const float* QKV, float* AO, float* sm) {
  const int t = threadIdx.x;
  float* qd  = sm;          // 256
  float* sc  = sm + 256;    // 384
  float* ao  = sm + 640;    // 256
  float* red = sm + 896;    // 16
  for (int pi = blockIdx.x; pi < 512; pi += gridDim.x) {
    int b = pi >> 3, h = pi & 7;
    const float* Qb = QKV + b*48*768 + h*32;
    const float* Kb = QKV + b*48*768 + 256 + h*32;
    const float* Vb = QKV + b*48*768 + 512 + h*32;
    for (int qg = 0; qg < 6; qg++) {
      { int r = t >> 5, d2 = t & 31; qd[r*32 + d2] = Qb[(qg*8 + r)*768 + d2]; }
      __syncthreads();
      attn_core(qd, Kb, Vb, 0, 768, 48, sc, red, ao);
      { int r = t >> 5, d2 = t & 31; AO[(b*48 + qg*8 + r)*256 + h*32 + d2] = ao[r*32 + d2]; }
      __syncthreads();
    }
  }
}

// ================= decode stages (64 WGs, 8 batch rows per WG) =================

static __device__ void d1_stage(const GParams& P, float* ws, int i, int l, float* sm) {
  const int wg = blockIdx.x, t = threadIdx.x;
  const int h = wg >> 3, bc = wg & 7;
  float* yin = sm;            // 2048
  float* qd  = sm + 2048;     // 256
  float* sc  = sm + 2304;     // 384
  float* ao  = sm + 2688;     // 256
  float* red = sm + 2944;     // 32
  if (l == 0) {
#pragma unroll
    for (int r = 0; r < 8; r++) yin[r*256 + t] = ws[Y0_OFF + (bc*8 + r)*256 + t];
    __syncthreads();
  } else {
    build_rows_ln(ws + Y2B_OFF, P.db2 + (l-1)*256, ws + FP_OFF,
                  P.dlnw + ((l-1)*3 + 2)*256, P.dlnb + ((l-1)*3 + 2)*256, bc*8, 8, yin);
  }
  if (h == 0) {
#pragma unroll
    for (int r = 0; r < 8; r++) ws[YIN_OFF + (bc*8 + r)*256 + t] = yin[r*256 + t];
  }
  // qkv for this head (writes K,V cache at position i; q stays in LDS)
  if (t < 192) {
    const int cq = t % 96, rh = t / 96;
    int wrowidx = (cq < 32) ? (h*32 + cq) : (cq < 64) ? (256 + h*32 + cq - 32) : (512 + h*32 + cq - 64);
    const float4* wr4 = (const float4*)(P.swqkv + (l*768 + wrowidx)*256);
    float acc[4] = {0,0,0,0};
    for (int k4 = 0; k4 < 64; k4++) {
      float4 w4 = wr4[k4];
#pragma unroll
      for (int rr = 0; rr < 4; rr++) {
        float4 a4 = *(const float4*)(yin + (rh*4 + rr)*256 + k4*4);
        acc[rr] += a4.x*w4.x; acc[rr] += a4.y*w4.y; acc[rr] += a4.z*w4.z; acc[rr] += a4.w*w4.w;
      }
    }
    float bqv = P.sbqkv[l*768 + wrowidx];
#pragma unroll
    for (int rr = 0; rr < 4; rr++) {
      int r = rh*4 + rr, b = bc*8 + r;
      float v = acc[rr] + bqv;
      if (cq < 32)      qd[r*32 + cq] = v;
      else if (cq < 64) ws[SK_OFF + (l*3072 + b*48 + i)*256 + h*32 + (cq - 32)] = v;
      else              ws[SV_OFF + (l*3072 + b*48 + i)*256 + h*32 + (cq - 64)] = v;
    }
  }
  __syncthreads();
  attn_core(qd, ws + SK_OFF + (l*3072 + bc*8*48)*256 + h*32,
                ws + SV_OFF + (l*3072 + bc*8*48)*256 + h*32,
            48*256, 256, i + 1, sc, red, ao);
  // partial out-projection for this head
  {
    const int c = t;
    const float* wr = P.swo + (l*256 + c)*256 + h*32;
    float acc[8] = {0,0,0,0,0,0,0,0};
    for (int d2 = 0; d2 < 32; d2++) {
      float w = wr[d2];
#pragma unroll
      for (int r = 0; r < 8; r++) acc[r] += ao[r*32 + d2]*w;
    }
#pragma unroll
    for (int r = 0; r < 8; r++) ws[PO1_OFF + (h*64 + bc*8 + r)*256 + c] = acc[r];
  }
}

static __device__ void d2_stage(const GParams& P, float* ws, int i, int l, float* sm) {
  const int wg = blockIdx.x, t = threadIdx.x;
  const int h = wg >> 3, bc = wg & 7;
  float* y1  = sm;
  float* qd  = sm + 2048;
  float* sc  = sm + 2304;
  float* ao  = sm + 2688;
  float* red = sm + 2944;
  build_rows_ln(ws + YIN_OFF, P.sbo + l*256, ws + PO1_OFF,
                P.dlnw + (l*3 + 0)*256, P.dlnb + (l*3 + 0)*256, bc*8, 8, y1);
  if (h == 0) {
#pragma unroll
    for (int r = 0; r < 8; r++) ws[Y1B_OFF + (bc*8 + r)*256 + t] = y1[r*256 + t];
  }
  // cross-attention query
  {
    const int r = t >> 5, cq = t & 31;
    const float4* wr4 = (const float4*)(P.cwqkv + (l*768 + h*32 + cq)*256);
    const float4* y4  = (const float4*)(y1 + r*256);
    float a = 0.0f;
    for (int k4 = 0; k4 < 64; k4++) {
      float4 w4 = wr4[k4], a4 = y4[k4];
      a += a4.x*w4.x; a += a4.y*w4.y; a += a4.z*w4.z; a += a4.w*w4.w;
    }
    qd[r*32 + cq] = a + P.cbqkv[l*768 + h*32 + cq];
  }
  __syncthreads();
  attn_core(qd, ws + CK_OFF + (l*3072 + bc*8*48)*256 + h*32,
                ws + CV_OFF + (l*3072 + bc*8*48)*256 + h*32,
            48*256, 256, 48, sc, red, ao);
  {
    const int c = t;
    const float* wr = P.cwo + (l*256 + c)*256 + h*32;
    float acc[8] = {0,0,0,0,0,0,0,0};
    for (int d2 = 0; d2 < 32; d2++) {
      float w = wr[d2];
#pragma unroll
      for (int r = 0; r < 8; r++) acc[r] += ao[r*32 + d2]*w;
    }
#pragma unroll
    for (int r = 0; r < 8; r++) ws[PO2_OFF + (h*64 + bc*8 + r)*256 + c] = acc[r];
  }
}

static __device__ void d3_stage(const GParams& P, float* ws, int i, int l, float* sm) {
  const int wg = blockIdx.x, t = threadIdx.x;
  const int j = wg >> 3, bc = wg & 7;
  float* y2 = sm;             // 2048
  float* hj = sm + 2048;      // 1024
  build_rows_ln(ws + Y1B_OFF, P.cbo + l*256, ws + PO2_OFF,
                P.dlnw + (l*3 + 1)*256, P.dlnb + (l*3 + 1)*256, bc*8, 8, y2);
  if (j == 0) {
#pragma unroll
    for (int r = 0; r < 8; r++) ws[Y2B_OFF + (bc*8 + r)*256 + t] = y2[r*256 + t];
  }
  // ffn1 slice (128 cols), relu
  if (t < 128) {
    const int jc = t;
    const float4* wr4 = (const float4*)(P.dw1 + (l*1024 + j*128 + jc)*256);
    float acc[8] = {0,0,0,0,0,0,0,0};
    for (int k4 = 0; k4 < 64; k4++) {
      float4 w4 = wr4[k4];
#pragma unroll
      for (int r = 0; r < 8; r++) {
        float4 a4 = *(const float4*)(y2 + r*256 + k4*4);
        acc[r] += a4.x*w4.x; acc[r] += a4.y*w4.y; acc[r] += a4.z*w4.z; acc[r] += a4.w*w4.w;
      }
    }
    float b1v = P.db1[l*1024 + j*128 + jc];
#pragma unroll
    for (int r = 0; r < 8; r++) hj[r*128 + jc] = fmaxf(acc[r] + b1v, 0.0f);
  }
  __syncthreads();
  // ffn2 partial
  {
    const int c = t;
    const float* wr = P.dw2 + (l*256 + c)*1024 + j*128;
    float acc[8] = {0,0,0,0,0,0,0,0};
    for (int jc = 0; jc < 128; jc++) {
      float w = wr[jc];
#pragma unroll
      for (int r = 0; r < 8; r++) acc[r] += hj[r*128 + jc]*w;
    }
#pragma unroll
    for (int r = 0; r < 8; r++) ws[FP_OFF + (j*64 + bc*8 + r)*256 + c] = acc[r];
  }
}

static __device__ void head_stage(const GParams& P, float* ws, int i, float* sm) {
  const int wg = blockIdx.x, t = threadIdx.x;
  const int vs = wg >> 2, bg = wg & 3;   // 16 vocab slices x 4 row groups (16 rows each)
  float* yf = sm;                        // 4096
  build_rows_ln(ws + Y2B_OFF, P.db2 + 5*256, ws + FP_OFF,
                P.dlnw + (5*3 + 2)*256, P.dlnb + (5*3 + 2)*256, bg*16, 16, yf);
  {
    const int wv = t >> 6;
    for (int r = wv; r < 16; r += 4) wave_ln_row(yf + r*256, P.lnfw + 256, P.lnfb + 256);
    __syncthreads();
  }
  const int col = t & 63, rh = t >> 6;
  const int v = vs*64 + col;
  const float4* wr4 = (const float4*)(P.hw + (i*1024 + v)*256);
  float acc[4] = {0,0,0,0};
  for (int k4 = 0; k4 < 64; k4++) {
    float4 w4 = wr4[k4];
#pragma unroll
    for (int rr = 0; rr < 4; rr++) {
      float4 a4 = *(const float4*)(yf + (rh*4 + rr)*256 + k4*4);
      acc[rr] += a4.x*w4.x; acc[rr] += a4.y*w4.y; acc[rr] += a4.z*w4.z; acc[rr] += a4.w*w4.w;
    }
  }
  float hbv = P.hb[i*1024 + v];
#pragma unroll
  for (int rr = 0; rr < 4; rr++) {
    int b = bg*16 + rh*4 + rr;
    P.out[3072 + i*65536 + b*1024 + v] = acc[rr] + hbv;
  }
}

static __device__ void sample_stage(const GParams& P, float* ws, int i, float* sm) {
  const int b = blockIdx.x, t = threadIdx.x;
  float* bv = sm;
  int*   bi = (int*)(sm + 256);
  unsigned k0, k1;
  step_key(i, k0, k1);
  float bestv = -INFINITY; int besti = 0;
  const float4 lg4 = *(const float4*)(P.out + 3072 + i*65536 + b*1024 + t*4);
  const float lgs[4] = {lg4.x, lg4.y, lg4.z, lg4.w};
#pragma unroll
  for (int e = 0; e < 4; e++) {
    int v = t*4 + e;
    unsigned bits = gumbel_bits(k0, k1, b, v);
    float f = __uint_as_float((bits >> 9) | 0x3f800000u);
    float u = fmaxf(f - 1.0f, 1.17549435e-38f);
    float g = -logf(-logf(u));
    float z = g + lgs[e] / 0.1f;
    if (z > bestv) { bestv = z; besti = v; }
  }
  bv[t] = bestv; bi[t] = besti;
  __syncthreads();
  for (int s = 128; s > 0; s >>= 1) {
    if (t < s) {
      float ov = bv[t+s]; int oi = bi[t+s];
      if (ov > bv[t] || (ov == bv[t] && oi < bi[t])) { bv[t] = ov; bi[t] = oi; }
    }
    __syncthreads();
  }
  const int ch = bi[0];
  if (t == 0) {
    if (i < 32) P.out[b*32 + i] = (float)ch;
    else        P.out[2048 + b*16 + (i - 32)] = (float)ch;
  }
  // next token input: buf[:, i+1] = emb_tab[i][choice]  (store with pe[i+1] pre-added)
  ws[Y0_OFF + b*256 + t] = P.emb[(i*1024 + ch)*256 + t] + ws[PE_OFF + (i+1)*256 + t];
}

// ================= the single persistent kernel =================
__global__ void __launch_bounds__(256)
genrev3_kernel(GParams P) {
  __shared__ float sm[8448];
  float* ws = P.ws;
  const int wg = blockIdx.x;
  const int t  = threadIdx.x;

  // ---- E0: pe table, encoder embeddings, initial decoder token (sos + pe[0]) ----
  for (int rr = 0; rr < 12; rr++) {
    int row = wg*12 + rr;
    int b = row / 48, s = row % 48;
    int tok = (s < 32) ? P.xc[b*32 + s] : P.xct[b*16 + (s - 32)];
    ws[X_OFF + row*256 + t] = P.emb[(s*1024 + tok)*256 + t] + pe_val(s, t);
  }
  if (wg < 49)               ws[PE_OFF + wg*256 + t] = pe_val(wg, t);
  if (wg >= 64 && wg < 128)  ws[Y0_OFF + (wg - 64)*256 + t] = P.sos[t] + pe_val(0, t);
  gbar(&g_cntA, &g_genA, 256);

  // ---- encoder: 6 post-norm layers ----
  float* Xp = ws + X_OFF;
  for (int l = 0; l < 6; l++) {
    gemm_stage(Xp, P.ewqkv + l*768*256, P.ebqkv + l*768, nullptr, ws + QKV_OFF, 3072, 768, 256, 0, sm);
    gbar(&g_cntA, &g_genA, 256);
    enc_attn_stage(ws + QKV_OFF, ws + AO_OFF, sm);
    gbar(&g_cntA, &g_genA, 256);
    gemm_stage(ws + AO_OFF, P.ewo + l*256*256, P.ebo + l*256, Xp, ws + RES1_OFF, 3072, 256, 256, 0, sm);
    gbar(&g_cntA, &g_genA, 256);
    ln_stage(ws + RES1_OFF, P.elnw + (l*2 + 0)*256, P.elnb + (l*2 + 0)*256, ws + X1_OFF, 3072);
    gbar(&g_cntA, &g_genA, 256);
    gemm_stage(ws + X1_OFF, P.ew1 + l*1024*256, P.eb1 + l*1024, nullptr, ws + HB_OFF, 3072, 1024, 256, 1, sm);
    gbar(&g_cntA, &g_genA, 256);
    gemm_stage(ws + HB_OFF, P.ew2 + l*256*1024, P.eb2 + l*256, ws + X1_OFF, ws + RES2_OFF, 3072, 256, 1024, 0, sm);
    gbar(&g_cntA, &g_genA, 256);
    ln_stage(ws + RES2_OFF, P.elnw + (l*2 + 1)*256, P.elnb + (l*2 + 1)*256, Xp, 3072);
    gbar(&g_cntA, &g_genA, 256);
  }
  ln_stage(Xp, P.lnfw, P.lnfb, ws + MEM_OFF, 3072);
  gbar(&g_cntA, &g_genA, 256);
  // cross K/V for all 6 decoder layers (independent GEMMs, single barrier after)
  for (int l = 0; l < 6; l++) {
    gemm_stage(ws + MEM_OFF, P.cwqkv + (l*768 + 256)*256, P.cbqkv + l*768 + 256, nullptr,
               ws + CK_OFF + l*786432, 3072, 256, 256, 0, sm);
    gemm_stage(ws + MEM_OFF, P.cwqkv + (l*768 + 512)*256, P.cbqkv + l*768 + 512, nullptr,
               ws + CV_OFF + l*786432, 3072, 256, 256, 0, sm);
  }
  gbar(&g_cntA, &g_genA, 256);

  // only 64 WGs run the sequential decode; the rest exit (their CUs go idle)
  if (wg >= 64) return;

  for (int i = 0; i < 48; i++) {
    for (int l = 0; l < 6; l++) {
      d1_stage(P, ws, i, l, sm); gbar(&g_cntB, &g_genB, 64);
      d2_stage(P, ws, i, l, sm); gbar(&g_cntB, &g_genB, 64);
      d3_stage(P, ws, i, l, sm); gbar(&g_cntB, &g_genB, 64);
    }
    head_stage(P, ws, i, sm);   gbar(&g_cntB, &g_genB, 64);
    sample_stage(P, ws, i, sm); gbar(&g_cntB, &g_genB, 64);
  }
}

extern "C" void kernel_launch(void* const* d_in, const int* in_sizes, int n_in,
                              void* d_out, int out_size, void* d_ws, size_t ws_size,
                              hipStream_t stream) {
  (void)in_sizes; (void)n_in; (void)out_size; (void)ws_size;
  GParams p;
  p.xc    = (const int*)  d_in[0];
  p.xct   = (const int*)  d_in[1];
  p.sos   = (const float*)d_in[2];
  p.emb   = (const float*)d_in[3];
  p.hw    = (const float*)d_in[4];
  p.hb    = (const float*)d_in[5];
  p.ewqkv = (const float*)d_in[6];
  p.ebqkv = (const float*)d_in[7];
  p.ewo   = (const float*)d_in[8];
  p.ebo   = (const float*)d_in[9];
  p.ew1   = (const float*)d_in[10];
  p.eb1   = (const float*)d_in[11];
  p.ew2   = (const float*)d_in[12];
  p.eb2   = (const float*)d_in[13];
  p.elnw  = (const float*)d_in[14];
  p.elnb  = (const float*)d_in[15];
  p.swqkv = (const float*)d_in[16];
  p.sbqkv = (const float*)d_in[17];
  p.swo   = (const float*)d_in[18];
  p.sbo   = (const float*)d_in[19];
  p.cwqkv = (const float*)d_in[20];
  p.cbqkv = (const float*)d_in[21];
  p.cwo   = (const float*)d_in[22];
  p.cbo   = (const float*)d_in[23];
  p.dw1   = (const float*)d_in[24];
  p.db1   = (const float*)d_in[25];
  p.dw2   = (const float*)d_in[26];
  p.db2   = (const float*)d_in[27];
  p.dlnw  = (const float*)d_in[28];
  p.dlnb  = (const float*)d_in[29];
  p.lnfw  = (const float*)d_in[30];
  p.lnfb  = (const float*)d_in[31];
  p.out   = (float*)d_out;
  p.ws    = (float*)d_ws;
  hipLaunchKernelGGL(genrev3_kernel, dim3(256), dim3(256), 0, stream, p);
}

// Round 2
// 38992.636 us; speedup vs baseline: 1.4238x; 1.4238x over previous
//
#include <hip/hip_runtime.h>
#include <math.h>

// ===== jax threefry mode: 1 = partitionable (jax >= 0.4.36 default) =====
#define JAX_PARTITIONABLE 1

// ---- model dims: NL=6 D=256 FF=1024 V=1024 S=48 BS=64 H=8 DH=32 ----

// ---- workspace layout (float offsets) ----
static constexpr int PE_OFF  = 0;                        // (unused now)
static constexpr int X_OFF   = PE_OFF + 49*256;          // 3072*256
static constexpr int MEM_OFF = X_OFF + 3072*256;         // 3072*256
static constexpr int CK_OFF  = MEM_OFF + 3072*256;       // 6*3072*256
static constexpr int CV_OFF  = CK_OFF + 6*3072*256;
static constexpr int SK_OFF  = CV_OFF + 6*3072*256;
static constexpr int SV_OFF  = SK_OFF + 6*3072*256;
// encoder temporaries alias the (decode-only) self KV cache region:
static constexpr int QKV_OFF  = SK_OFF;                  // 3072*768
static constexpr int AO_OFF   = QKV_OFF + 3072*768;      // 3072*256
static constexpr int RES1_OFF = AO_OFF + 3072*256;       // 3072*256
static constexpr int X1_OFF   = RES1_OFF + 3072*256;     // 3072*256
static constexpr int HB_OFF   = SV_OFF;                  // 3072*1024
static constexpr int RES2_OFF = HB_OFF + 3072*1024;      // 3072*256

struct GParams {
  const int   *xc, *xct;
  const float *sos, *emb, *hw, *hb;
  const float *ewqkv, *ebqkv, *ewo, *ebo, *ew1, *eb1, *ew2, *eb2, *elnw, *elnb;
  const float *swqkv, *sbqkv, *swo, *sbo;
  const float *cwqkv, *cbqkv, *cwo, *cbo;
  const float *dw1, *db1, *dw2, *db2, *dlnw, *dlnb, *lnfw, *lnfb;
  float *out;
  float *ws;
};

// ---- device-global barrier state (generation counters survive graph replays) ----
__device__ unsigned g_cntA = 0, g_genA = 0;

static __device__ __forceinline__ void gbar(unsigned* cnt, unsigned* gen, unsigned nb) {
  __syncthreads();
  if (threadIdx.x == 0) {
    __threadfence();
    unsigned g = __hip_atomic_load(gen, __ATOMIC_RELAXED, __HIP_MEMORY_SCOPE_AGENT);
    unsigned prev = __hip_atomic_fetch_add(cnt, 1u, __ATOMIC_ACQ_REL, __HIP_MEMORY_SCOPE_AGENT);
    if (prev == nb - 1u) {
      __hip_atomic_store(cnt, 0u, __ATOMIC_RELAXED, __HIP_MEMORY_SCOPE_AGENT);
      __threadfence();
      __hip_atomic_store(gen, g + 1u, __ATOMIC_RELEASE, __HIP_MEMORY_SCOPE_AGENT);
    } else {
      while (__hip_atomic_load(gen, __ATOMIC_ACQUIRE, __HIP_MEMORY_SCOPE_AGENT) == g)
        __builtin_amdgcn_s_sleep(1);
      __threadfence();
    }
  }
  __syncthreads();
}

// ---- threefry2x32 (exact jax rotation/key schedule) ----
static __device__ __forceinline__ void tf2x32(unsigned k0, unsigned k1, unsigned& x0, unsigned& x1) {
  unsigned ks2 = k0 ^ k1 ^ 0x1BD11BDAu;
  x0 += k0; x1 += k1;
#define TF_R(r) { x0 += x1; x1 = (x1 << r) | (x1 >> (32 - r)); x1 ^= x0; }
  TF_R(13) TF_R(15) TF_R(26) TF_R(6)   x0 += k1;  x1 += ks2 + 1u;
  TF_R(17) TF_R(29) TF_R(16) TF_R(24)  x0 += ks2; x1 += k0  + 2u;
  TF_R(13) TF_R(15) TF_R(26) TF_R(6)   x0 += k0;  x1 += k1  + 3u;
  TF_R(17) TF_R(29) TF_R(16) TF_R(24)  x0 += k1;  x1 += ks2 + 4u;
  TF_R(13) TF_R(15) TF_R(26) TF_R(6)   x0 += ks2; x1 += k0  + 5u;
#undef TF_R
}

static __device__ __forceinline__ void step_key(int i, unsigned& k0, unsigned& k1) {
#if JAX_PARTITIONABLE
  unsigned x0 = 0u, x1 = (unsigned)i;
  tf2x32(0u, 42u, x0, x1);
  k0 = x0; k1 = x1;
#else
  unsigned w[2];
  for (int wi = 0; wi < 2; wi++) {
    unsigned o = (unsigned)(2*i + wi), x0, x1;
    if (o < 48u) { x0 = o; x1 = 48u + o; tf2x32(0u, 42u, x0, x1); w[wi] = x0; }
    else         { x0 = o - 48u; x1 = o; tf2x32(0u, 42u, x0, x1); w[wi] = x1; }
  }
  k0 = w[0]; k1 = w[1];
#endif
}

static __device__ __forceinline__ unsigned gumbel_bits(unsigned k0, unsigned k1, int b, int v) {
#if JAX_PARTITIONABLE
  unsigned x0 = 0u, x1 = (unsigned)(b*1024 + v);
  tf2x32(k0, k1, x0, x1);
  return x0 ^ x1;
#else
  unsigned jj = (unsigned)((b & 31)*1024 + v);
  unsigned x0 = jj, x1 = 32768u + jj;
  tf2x32(k0, k1, x0, x1);
  return (b < 32) ? x0 : x1;
#endif
}

// ---- positional encoding element (same bits as round-1 passing kernel) ----
static __device__ __forceinline__ float pe_val(int p, int c) {
  const float KC = (float)(-9.210340371976184 / 256.0);
  int j = c >> 1;
  float dv = expf((float)(2*j) * KC);
  float a = (float)p * dv;
  return (c & 1) ? cosf(a) : sinf(a);
}

// ---- per-wave LayerNorm of a 256-float LDS row (two-pass; call with one wave) ----
static __device__ __forceinline__ void wave_ln_row(float* row, const float* lw, const float* lb) {
  const int lane = threadIdx.x & 63;
  float x0 = row[lane], x1 = row[lane+64], x2 = row[lane+128], x3 = row[lane+192];
  float s = (x0 + x1) + (x2 + x3);
#pragma unroll
  for (int m = 1; m < 64; m <<= 1) s += __shfl_xor(s, m);
  float mean = s * 0.00390625f;
  float d0 = x0-mean, d1 = x1-mean, d2 = x2-mean, d3 = x3-mean;
  float q = (d0*d0 + d1*d1) + (d2*d2 + d3*d3);
#pragma unroll
  for (int m = 1; m < 64; m <<= 1) q += __shfl_xor(q, m);
  float rs = 1.0f / sqrtf(q * 0.00390625f + 1e-5f);
  row[lane]     = d0*rs*lw[lane]     + lb[lane];
  row[lane+64]  = d1*rs*lw[lane+64]  + lb[lane+64];
  row[lane+128] = d2*rs*lw[lane+128] + lb[lane+128];
  row[lane+192] = d3*rs*lw[lane+192] + lb[lane+192];
}

// ---- strict-ascending dot products (sequential accumulate, float4 loads) ----
static __device__ __forceinline__ float dot256(const float* x, const float* w) {
  const float4* x4 = (const float4*)x;
  const float4* w4 = (const float4*)w;
  float acc = 0.0f;
#pragma unroll 8
  for (int k = 0; k < 64; k++) {
    float4 a4 = x4[k], b4 = w4[k];
    acc += a4.x*b4.x; acc += a4.y*b4.y; acc += a4.z*b4.z; acc += a4.w*b4.w;
  }
  return acc;
}
static __device__ __forceinline__ float dot1024(const float* x, const float* w) {
  const float4* x4 = (const float4*)x;
  const float4* w4 = (const float4*)w;
  float acc = 0.0f;
#pragma unroll 8
  for (int k = 0; k < 256; k++) {
    float4 a4 = x4[k], b4 = w4[k];
    acc += a4.x*b4.x; acc += a4.y*b4.y; acc += a4.z*b4.z; acc += a4.w*b4.w;
  }
  return acc;
}

// ---- generic tiled GEMM stage (encoder; 256 active threads of the 512) ----
static __device__ void gemm_stage(const float* __restrict__ A, const float* __restrict__ W,
                                  const float* __restrict__ bias, const float* __restrict__ res,
                                  float* __restrict__ out, int R, int C, int K, int relu,
                                  float* sA) {
  const int t = threadIdx.x;
  const bool act = (t < 256);
  const int lane = t & 63, wv = (t >> 6) & 3;
  const int ntc = C >> 6;
  const int ntiles = (R >> 5) * ntc;
  for (int tile = blockIdx.x; tile < ntiles; tile += gridDim.x) {
    const int tr = tile / ntc, tc = tile - tr*ntc;
    const int r0 = tr << 5;
    const int c  = (tc << 6) + lane;
    float acc[8] = {0,0,0,0,0,0,0,0};
    for (int kc = 0; kc < K; kc += 256) {
      __syncthreads();
      if (act) {
#pragma unroll
        for (int u = 0; u < 8; u++) {
          int idx = u*256 + t;
          int rr = idx >> 6, cc = idx & 63;
          ((float4*)sA)[idx] = *(const float4*)(A + (r0+rr)*K + kc + cc*4);
        }
      }
      __syncthreads();
      if (act) {
        const float* wr = W + c*K + kc;
        for (int k = 0; k < 256; k += 4) {
          float4 w4 = *(const float4*)(wr + k);
#pragma unroll
          for (int r = 0; r < 8; r++) {
            float4 a4 = *(const float4*)(sA + (wv*8 + r)*256 + k);
            acc[r] += a4.x*w4.x; acc[r] += a4.y*w4.y; acc[r] += a4.z*w4.z; acc[r] += a4.w*w4.w;
          }
        }
      }
    }
    if (act) {
      float bb = bias ? bias[c] : 0.0f;
#pragma unroll
      for (int r = 0; r < 8; r++) {
        int row = r0 + wv*8 + r;
        float v = acc[r] + bb;
        if (relu) v = fmaxf(v, 0.0f);
        if (res)  v += res[row*C + c];
        out[row*C + c] = v;
      }
    }
  }
}

// ---- standalone LN stage (encoder): out = LN(in), R rows of 256; 8 waves ----
static __device__ void ln_stage(const float* in, const float* lw, const float* lb,
                                float* out, int R) {
  const int lane = threadIdx.x & 63;
  int gw = blockIdx.x*8 + (threadIdx.x >> 6);
  for (int row = gw; row < R; row += gridDim.x*8) {
    const float* ir = in + row*256;
    float x0 = ir[lane], x1 = ir[lane+64], x2 = ir[lane+128], x3 = ir[lane+192];
    float s = (x0 + x1) + (x2 + x3);
#pragma unroll
    for (int m = 1; m < 64; m <<= 1) s += __shfl_xor(s, m);
    float mean = s * 0.00390625f;
    float d0 = x0-mean, d1 = x1-mean, d2 = x2-mean, d3 = x3-mean;
    float q = (d0*d0 + d1*d1) + (d2*d2 + d3*d3);
#pragma unroll
    for (int m = 1; m < 64; m <<= 1) q += __shfl_xor(q, m);
    float rs = 1.0f / sqrtf(q * 0.00390625f + 1e-5f);
    float* orow = out + row*256;
    orow[lane]     = d0*rs*lw[lane]     + lb[lane];
    orow[lane+64]  = d1*rs*lw[lane+64]  + lb[lane+64];
    orow[lane+128] = d2*rs*lw[lane+128] + lb[lane+128];
    orow[lane+192] = d3*rs*lw[lane+192] + lb[lane+192];
  }
}

// ---- attention core: 8 "rows" (r=t>>5; encoder: 8 query rows, decode: 8 heads)
//      vs nk keys; threads >=256 only participate in the barriers ----
static __device__ void attn_core(const float* qd, const float* kb, const float* vb,
                                 int krstride, int kstride, int nk,
                                 float* sc, float* red, float* ao) {
  const int t = threadIdx.x;
  const int r = t >> 5, p0 = t & 31;
  const bool act = (t < 256);
  if (act) {
#pragma unroll
    for (int pass = 0; pass < 2; pass++) {
      int p = pass*32 + p0;
      if (p < nk) {
        const float4* k4 = (const float4*)(kb + r*krstride + p*kstride);
        const float4* q4 = (const float4*)(qd + r*32);
        float a = 0.0f;
#pragma unroll
        for (int d4 = 0; d4 < 8; d4++) {
          float4 kv = k4[d4], qv = q4[d4];
          a += qv.x*kv.x; a += qv.y*kv.y; a += qv.z*kv.z; a += qv.w*kv.w;
        }
        sc[r*48 + p] = a * 0.17677669529663687f; // 1/sqrt(32)
      }
    }
  }
  __syncthreads();
  if (t < 8) {
    float m = sc[t*48];
    for (int p = 1; p < nk; p++) m = fmaxf(m, sc[t*48 + p]);
    red[t] = m;
  }
  __syncthreads();
  if (act) {
#pragma unroll
    for (int pass = 0; pass < 2; pass++) {
      int p = pass*32 + p0;
      if (p < nk) sc[r*48 + p] = expf(sc[r*48 + p] - red[r]);
    }
  }
  __syncthreads();
  if (t < 8) {
    float s = 0.0f;
    for (int p = 0; p < nk; p++) s += sc[t*48 + p];
    red[8 + t] = s;
  }
  __syncthreads();
  if (act) {
#pragma unroll
    for (int pass = 0; pass < 2; pass++) {
      int p = pass*32 + p0;
      if (p < nk) sc[r*48 + p] = sc[r*48 + p] / red[8 + r];
    }
  }
  __syncthreads();
  if (act) {
    const int d2 = t & 31;
    const float* vr = vb + r*krstride + d2;
    float a = 0.0f;
    for (int p = 0; p < nk; p++) a += sc[r*48 + p] * vr[p*kstride];
    ao[r*32 + d2] = a;
  }
  __syncthreads();
}

// ---- encoder attention stage: full (no mask), per (b,h) pair ----
static __device__ void enc_attn_stage(const float* QKV, float* AO, float* sm) {
  const int t = threadIdx.x;
  const bool act = (t < 256);
  float* qd  = sm;          // 256
  float* sc  = sm + 256;    // 384
  float* ao  = sm + 640;    // 256
  float* red = sm + 896;    // 16
  for (int pi = blockIdx.x; pi < 512; pi += gridDim.x) {
    int b = pi >> 3, h = pi & 7;
    const float* Qb = QKV + b*48*768 + h*32;
    const float* Kb = QKV + b*48*768 + 256 + h*32;
    const float* Vb = QKV + b*48*768 + 512 + h*32;
    for (int qg = 0; qg < 6; qg++) {
      if (act) { int r = t >> 5, d2 = t & 31; qd[r*32 + d2] = Qb[(qg*8 + r)*768 + d2]; }
      __syncthreads();
      attn_core(qd, Kb, Vb, 0, 768, 48, sc, red, ao);
      if (act) { int r = t >> 5, d2 = t & 31; AO[(b*48 + qg*8 + r)*256 + h*32 + d2] = ao[r*32 + d2]; }
      __syncthreads();
    }
  }
}

// ================= the single persistent kernel =================
__global__ void __launch_bounds__(512)
genrev3_kernel(GParams P) {
  __shared__ float sm[8448];
  float* ws = P.ws;
  const int wg = blockIdx.x;
  const int t  = threadIdx.x;

  // ---- E0: encoder embeddings + pe ----
  if (t < 256) {
    for (int rr = 0; rr < 12; rr++) {
      int row = wg*12 + rr;
      int b = row / 48, s = row % 48;
      int tok = (s < 32) ? P.xc[b*32 + s] : P.xct[b*16 + (s - 32)];
      ws[X_OFF + row*256 + t] = P.emb[(s*1024 + tok)*256 + t] + pe_val(s, t);
    }
  }
  gbar(&g_cntA, &g_genA, 256);

  // ---- encoder: 6 post-norm layers (unchanged structure from round 1) ----
  float* Xp = ws + X_OFF;
  for (int l = 0; l < 6; l++) {
    gemm_stage(Xp, P.ewqkv + l*768*256, P.ebqkv + l*768, nullptr, ws + QKV_OFF, 3072, 768, 256, 0, sm);
    gbar(&g_cntA, &g_genA, 256);
    enc_attn_stage(ws + QKV_OFF, ws + AO_OFF, sm);
    gbar(&g_cntA, &g_genA, 256);
    gemm_stage(ws + AO_OFF, P.ewo + l*256*256, P.ebo + l*256, Xp, ws + RES1_OFF, 3072, 256, 256, 0, sm);
    gbar(&g_cntA, &g_genA, 256);
    ln_stage(ws + RES1_OFF, P.elnw + (l*2 + 0)*256, P.elnb + (l*2 + 0)*256, ws + X1_OFF, 3072);
    gbar(&g_cntA, &g_genA, 256);
    gemm_stage(ws + X1_OFF, P.ew1 + l*1024*256, P.eb1 + l*1024, nullptr, ws + HB_OFF, 3072, 1024, 256, 1, sm);
    gbar(&g_cntA, &g_genA, 256);
    gemm_stage(ws + HB_OFF, P.ew2 + l*256*1024, P.eb2 + l*256, ws + X1_OFF, ws + RES2_OFF, 3072, 256, 1024, 0, sm);
    gbar(&g_cntA, &g_genA, 256);
    ln_stage(ws + RES2_OFF, P.elnw + (l*2 + 1)*256, P.elnb + (l*2 + 1)*256, Xp, 3072);
    gbar(&g_cntA, &g_genA, 256);
  }
  ln_stage(Xp, P.lnfw, P.lnfb, ws + MEM_OFF, 3072);
  gbar(&g_cntA, &g_genA, 256);
  for (int l = 0; l < 6; l++) {
    gemm_stage(ws + MEM_OFF, P.cwqkv + (l*768 + 256)*256, P.cbqkv + l*768 + 256, nullptr,
               ws + CK_OFF + l*786432, 3072, 256, 256, 0, sm);
    gemm_stage(ws + MEM_OFF, P.cwqkv + (l*768 + 512)*256, P.cbqkv + l*768 + 512, nullptr,
               ws + CV_OFF + l*786432, 3072, 256, 256, 0, sm);
  }
  gbar(&g_cntA, &g_genA, 256);   // last device-scope barrier; acquire fence makes CK/CV visible

  // ================= barrier-free per-row decode: WG b owns batch row b =================
  if (wg >= 64) return;
  const int b = wg;

  float* cur = sm;          // 256  current layer input (post-LN)
  float* qv  = sm + 256;    // 256
  float* av  = sm + 512;    // 256  attention output
  float* y1  = sm + 768;    // 256
  float* y2  = sm + 1024;   // 256
  float* hbf = sm + 1280;   // 1024 ffn hidden / logits
  float* sc  = sm + 2304;   // 384
  float* red = sm + 2688;   // 16
  float* y0  = sm + 2720;   // 256  next-token input (emb + pe)
  float* bvv = sm + 2976;   // 256  sampling reduce values
  int*   bii = (int*)(sm + 3232); // 256 sampling reduce indices

  if (t < 256) y0[t] = P.sos[t] + pe_val(0, t);
  __syncthreads();

  for (int i = 0; i < 48; i++) {
    if (t < 256) cur[t] = y0[t];
    __syncthreads();
    for (int l = 0; l < 6; l++) {
      // --- self-attention QKV (q -> LDS, k/v -> per-row cache at pos i) ---
      for (int o = t; o < 768; o += 512) {
        float v = dot256(cur, P.swqkv + (l*768 + o)*256) + P.sbqkv[l*768 + o];
        if (o < 256)      qv[o] = v;
        else if (o < 512) ws[SK_OFF + (l*3072 + b*48 + i)*256 + (o - 256)] = v;
        else              ws[SV_OFF + (l*3072 + b*48 + i)*256 + (o - 512)] = v;
      }
      __syncthreads();
      attn_core(qv, ws + SK_OFF + (l*3072 + b*48)*256, ws + SV_OFF + (l*3072 + b*48)*256,
                32, 256, i + 1, sc, red, av);
      // --- self out-proj + residual + LN ---
      if (t < 256)
        y1[t] = cur[t] + (dot256(av, P.swo + (l*256 + t)*256) + P.sbo[l*256 + t]);
      __syncthreads();
      if (t < 64) wave_ln_row(y1, P.dlnw + (l*3 + 0)*256, P.dlnb + (l*3 + 0)*256);
      __syncthreads();
      // --- cross-attention ---
      if (t < 256)
        qv[t] = dot256(y1, P.cwqkv + (l*768 + t)*256) + P.cbqkv[l*768 + t];
      __syncthreads();
      attn_core(qv, ws + CK_OFF + (l*3072 + b*48)*256, ws + CV_OFF + (l*3072 + b*48)*256,
                32, 256, 48, sc, red, av);
      if (t < 256)
        y2[t] = y1[t] + (dot256(av, P.cwo + (l*256 + t)*256) + P.cbo[l*256 + t]);
      __syncthreads();
      if (t < 64) wave_ln_row(y2, P.dlnw + (l*3 + 1)*256, P.dlnb + (l*3 + 1)*256);
      __syncthreads();
      // --- FFN ---
      for (int o = t; o < 1024; o += 512)
        hbf[o] = fmaxf(dot256(y2, P.dw1 + (l*1024 + o)*256) + P.db1[l*1024 + o], 0.0f);
      __syncthreads();
      if (t < 256)
        cur[t] = y2[t] + (dot1024(hbf, P.dw2 + (l*256 + t)*1024) + P.db2[l*256 + t]);
      __syncthreads();
      if (t < 64) wave_ln_row(cur, P.dlnw + (l*3 + 2)*256, P.dlnb + (l*3 + 2)*256);
      __syncthreads();
    }
    // --- final LN (lnf[1]) ---
    if (t < 64) wave_ln_row(cur, P.lnfw + 256, P.lnfb + 256);
    __syncthreads();
    // --- head: logits ---
    for (int o = t; o < 1024; o += 512) {
      float lg = dot256(cur, P.hw + (i*1024 + o)*256) + P.hb[i*1024 + o];
      hbf[o] = lg;
      P.out[3072 + i*65536 + b*1024 + o] = lg;
    }
    __syncthreads();
    // --- gumbel-argmax sampling (identical structure to round-1 passing kernel) ---
    unsigned k0, k1;
    step_key(i, k0, k1);
    if (t < 256) {
      float bestv = -INFINITY; int besti = 0;
#pragma unroll
      for (int e = 0; e < 4; e++) {
        int v = t*4 + e;
        unsigned bits = gumbel_bits(k0, k1, b, v);
        float f = __uint_as_float((bits >> 9) | 0x3f800000u);
        float u = fmaxf(f - 1.0f, 1.17549435e-38f);
        float g = -logf(-logf(u));
        float z = g + hbf[v] / 0.1f;
        if (z > bestv) { bestv = z; besti = v; }
      }
      bvv[t] = bestv; bii[t] = besti;
    }
    __syncthreads();
    for (int s = 128; s > 0; s >>= 1) {
      if (t < s) {
        float ov = bvv[t+s]; int oi = bii[t+s];
        if (ov > bvv[t] || (ov == bvv[t] && oi < bii[t])) { bvv[t] = ov; bii[t] = oi; }
      }
      __syncthreads();
    }
    const int ch = bii[0];
    if (t == 0) {
      if (i < 32) P.out[b*32 + i] = (float)ch;
      else        P.out[2048 + b*16 + (i - 32)] = (float)ch;
    }
    if (t < 256) y0[t] = P.emb[(i*1024 + ch)*256 + t] + pe_val(i + 1, t);
    __syncthreads();
  }
}

extern "C" void kernel_launch(void* const* d_in, const int* in_sizes, int n_in,
                              void* d_out, int out_size, void* d_ws, size_t ws_size,
                              hipStream_t stream) {
  (void)in_sizes; (void)n_in; (void)out_size; (void)ws_size;
  GParams p;
  p.xc    = (const int*)  d_in[0];
  p.xct   = (const int*)  d_in[1];
  p.sos   = (const float*)d_in[2];
  p.emb   = (const float*)d_in[3];
  p.hw    = (const float*)d_in[4];
  p.hb    = (const float*)d_in[5];
  p.ewqkv = (const float*)d_in[6];
  p.ebqkv = (const float*)d_in[7];
  p.ewo   = (const float*)d_in[8];
  p.ebo   = (const float*)d_in[9];
  p.ew1   = (const float*)d_in[10];
  p.eb1   = (const float*)d_in[11];
  p.ew2   = (const float*)d_in[12];
  p.eb2   = (const float*)d_in[13];
  p.elnw  = (const float*)d_in[14];
  p.elnb  = (const float*)d_in[15];
  p.swqkv = (const float*)d_in[16];
  p.sbqkv = (const float*)d_in[17];
  p.swo   = (const float*)d_in[18];
  p.sbo   = (const float*)d_in[19];
  p.cwqkv = (const float*)d_in[20];
  p.cbqkv = (const float*)d_in[21];
  p.cwo   = (const float*)d_in[22];
  p.cbo   = (const float*)d_in[23];
  p.dw1   = (const float*)d_in[24];
  p.db1   = (const float*)d_in[25];
  p.dw2   = (const float*)d_in[26];
  p.db2   = (const float*)d_in[27];
  p.dlnw  = (const float*)d_in[28];
  p.dlnb  = (const float*)d_in[29];
  p.lnfw  = (const float*)d_in[30];
  p.lnfb  = (const float*)d_in[31];
  p.out   = (float*)d_out;
  p.ws    = (float*)d_ws;
  hipLaunchKernelGGL(genrev3_kernel, dim3(256), dim3(512), 0, stream, p);
}

// Round 3
// 30849.207 us; speedup vs baseline: 1.7997x; 1.2640x over previous
//
#include <hip/hip_runtime.h>
#include <math.h>

// ===== jax threefry mode: 1 = partitionable (jax >= 0.4.36 default) =====
#define JAX_PARTITIONABLE 1

// ---- model dims: NL=6 D=256 FF=1024 V=1024 S=48 BS=64 H=8 DH=32 ----

// ---- workspace layout (float offsets) ----
// Transposed decode weights (built after encoder; region doubles as X/MEM during encoder)
static constexpr int SWQKVT  = 0;                        // 6 x [256 k][768 o]
static constexpr int SWOT    = SWQKVT + 6*256*768;       // 1,179,648 ; 6 x [256][256]
static constexpr int CWQT    = SWOT   + 6*256*256;       // 1,572,864
static constexpr int CWOT    = CWQT   + 6*256*256;       // 1,966,080
static constexpr int DW1T    = CWOT   + 6*256*256;       // 2,359,296 ; 6 x [256][1024]
static constexpr int DW2T    = DW1T   + 6*256*1024;      // 3,932,160 ; 6 x [1024][256]
static constexpr int WT_END  = DW2T   + 6*1024*256;      // 5,505,024
static constexpr int CKT_OFF = WT_END;                   // 6 x 64 x [64 d4][48 p][4 c]
static constexpr int CV_OFF  = CKT_OFF + 6*64*48*256;    // 10,223,616 ; [l][b*48+p][256]
static constexpr int SKT_OFF = CV_OFF  + 6*64*48*256;    // 14,942,208
static constexpr int SV_OFF  = SKT_OFF + 6*64*48*256;    // 19,660,800
static constexpr int WS_END  = SV_OFF  + 6*64*48*256;    // 24,379,392 floats = 97.5 MB
// encoder-time aliases (dead before the regions' real use):
static constexpr int X_OFF    = 0;                       // 786,432 (inside SWQKVT)
static constexpr int MEM_OFF  = X_OFF + 3072*256;        // 786,432..1,572,864 (inside SWQKVT)
static constexpr int QKV_OFF  = SKT_OFF;                 // 2,359,296
static constexpr int AO_OFF   = QKV_OFF + 3072*768;      // 786,432
static constexpr int RES1_OFF = AO_OFF + 3072*256;
static constexpr int X1_OFF   = RES1_OFF + 3072*256;     // ends exactly at SV_OFF
static constexpr int HB_OFF   = SV_OFF;                  // 3,145,728
static constexpr int RES2_OFF = HB_OFF + 3072*1024;      // fits before WS_END
// plain cross-K (pre-transpose temp) lives at SKT_OFF (dead before decode writes SKT)
static constexpr int PCK_OFF  = SKT_OFF;

struct GParams {
  const int   *xc, *xct;
  const float *sos, *emb, *hw, *hb;
  const float *ewqkv, *ebqkv, *ewo, *ebo, *ew1, *eb1, *ew2, *eb2, *elnw, *elnb;
  const float *swqkv, *sbqkv, *swo, *sbo;
  const float *cwqkv, *cbqkv, *cwo, *cbo;
  const float *dw1, *db1, *dw2, *db2, *dlnw, *dlnb, *lnfw, *lnfb;
  float *out;
  float *ws;
};

// ---- device-global barrier state (generation counters survive graph replays) ----
__device__ unsigned g_cntA = 0, g_genA = 0;

static __device__ __forceinline__ void gbar(unsigned* cnt, unsigned* gen, unsigned nb) {
  __syncthreads();
  if (threadIdx.x == 0) {
    __threadfence();
    unsigned g = __hip_atomic_load(gen, __ATOMIC_RELAXED, __HIP_MEMORY_SCOPE_AGENT);
    unsigned prev = __hip_atomic_fetch_add(cnt, 1u, __ATOMIC_ACQ_REL, __HIP_MEMORY_SCOPE_AGENT);
    if (prev == nb - 1u) {
      __hip_atomic_store(cnt, 0u, __ATOMIC_RELAXED, __HIP_MEMORY_SCOPE_AGENT);
      __threadfence();
      __hip_atomic_store(gen, g + 1u, __ATOMIC_RELEASE, __HIP_MEMORY_SCOPE_AGENT);
    } else {
      while (__hip_atomic_load(gen, __ATOMIC_ACQUIRE, __HIP_MEMORY_SCOPE_AGENT) == g)
        __builtin_amdgcn_s_sleep(1);
      __threadfence();
    }
  }
  __syncthreads();
}

// ---- threefry2x32 (exact jax rotation/key schedule) ----
static __device__ __forceinline__ void tf2x32(unsigned k0, unsigned k1, unsigned& x0, unsigned& x1) {
  unsigned ks2 = k0 ^ k1 ^ 0x1BD11BDAu;
  x0 += k0; x1 += k1;
#define TF_R(r) { x0 += x1; x1 = (x1 << r) | (x1 >> (32 - r)); x1 ^= x0; }
  TF_R(13) TF_R(15) TF_R(26) TF_R(6)   x0 += k1;  x1 += ks2 + 1u;
  TF_R(17) TF_R(29) TF_R(16) TF_R(24)  x0 += ks2; x1 += k0  + 2u;
  TF_R(13) TF_R(15) TF_R(26) TF_R(6)   x0 += k0;  x1 += k1  + 3u;
  TF_R(17) TF_R(29) TF_R(16) TF_R(24)  x0 += k1;  x1 += ks2 + 4u;
  TF_R(13) TF_R(15) TF_R(26) TF_R(6)   x0 += ks2; x1 += k0  + 5u;
#undef TF_R
}

static __device__ __forceinline__ void step_key(int i, unsigned& k0, unsigned& k1) {
#if JAX_PARTITIONABLE
  unsigned x0 = 0u, x1 = (unsigned)i;
  tf2x32(0u, 42u, x0, x1);
  k0 = x0; k1 = x1;
#else
  unsigned w[2];
  for (int wi = 0; wi < 2; wi++) {
    unsigned o = (unsigned)(2*i + wi), x0, x1;
    if (o < 48u) { x0 = o; x1 = 48u + o; tf2x32(0u, 42u, x0, x1); w[wi] = x0; }
    else         { x0 = o - 48u; x1 = o; tf2x32(0u, 42u, x0, x1); w[wi] = x1; }
  }
  k0 = w[0]; k1 = w[1];
#endif
}

static __device__ __forceinline__ unsigned gumbel_bits(unsigned k0, unsigned k1, int b, int v) {
#if JAX_PARTITIONABLE
  unsigned x0 = 0u, x1 = (unsigned)(b*1024 + v);
  tf2x32(k0, k1, x0, x1);
  return x0 ^ x1;
#else
  unsigned jj = (unsigned)((b & 31)*1024 + v);
  unsigned x0 = jj, x1 = 32768u + jj;
  tf2x32(k0, k1, x0, x1);
  return (b < 32) ? x0 : x1;
#endif
}

// ---- positional encoding element ----
static __device__ __forceinline__ float pe_val(int p, int c) {
  const float KC = (float)(-9.210340371976184 / 256.0);
  int j = c >> 1;
  float dv = expf((float)(2*j) * KC);
  float a = (float)p * dv;
  return (c & 1) ? cosf(a) : sinf(a);
}

// ---- per-wave LayerNorm of a 256-float LDS row (call with one full wave) ----
static __device__ __forceinline__ void wave_ln_row(float* row, const float* lw, const float* lb) {
  const int lane = threadIdx.x & 63;
  float x0 = row[lane], x1 = row[lane+64], x2 = row[lane+128], x3 = row[lane+192];
  float s = (x0 + x1) + (x2 + x3);
#pragma unroll
  for (int m = 1; m < 64; m <<= 1) s += __shfl_xor(s, m);
  float mean = s * 0.00390625f;
  float d0 = x0-mean, d1 = x1-mean, d2 = x2-mean, d3 = x3-mean;
  float q = (d0*d0 + d1*d1) + (d2*d2 + d3*d3);
#pragma unroll
  for (int m = 1; m < 64; m <<= 1) q += __shfl_xor(q, m);
  float rs = 1.0f / sqrtf(q * 0.00390625f + 1e-5f);
  row[lane]     = d0*rs*lw[lane]     + lb[lane];
  row[lane+64]  = d1*rs*lw[lane+64]  + lb[lane+64];
  row[lane+128] = d2*rs*lw[lane+128] + lb[lane+128];
  row[lane+192] = d3*rs*lw[lane+192] + lb[lane+192];
}

// ---- transposed coalesced matvec partials: wt is [K][C] (k-major), x in LDS ----
// thread t: kc = t/(C/4) k-chunk, o4 = t%(C/4); acc float4 over its chunk, store to part[kc*C + o].
template<int C, int KS, int K>
static __device__ void matvec_t(const float* __restrict__ wt, const float* __restrict__ x,
                                float* __restrict__ part) {
  const int t = threadIdx.x;
  constexpr int O4 = C/4;
  constexpr int KC = K/KS;
  if (t < O4*KS) {
    const int kc = t / O4, o4 = t - kc*O4;
    const int k0 = kc*KC;
    float4 acc = {0.f,0.f,0.f,0.f};
    const float* wp = wt + k0*C + o4*4;
#pragma unroll 4
    for (int k = 0; k < KC; k += 4) {
      float4 xv = *(const float4*)(x + k0 + k);
      float4 w0 = *(const float4*)(wp + (k+0)*C);
      float4 w1 = *(const float4*)(wp + (k+1)*C);
      float4 w2 = *(const float4*)(wp + (k+2)*C);
      float4 w3 = *(const float4*)(wp + (k+3)*C);
      acc.x += xv.x*w0.x; acc.y += xv.x*w0.y; acc.z += xv.x*w0.z; acc.w += xv.x*w0.w;
      acc.x += xv.y*w1.x; acc.y += xv.y*w1.y; acc.z += xv.y*w1.z; acc.w += xv.y*w1.w;
      acc.x += xv.z*w2.x; acc.y += xv.z*w2.y; acc.z += xv.z*w2.z; acc.w += xv.z*w2.w;
      acc.x += xv.w*w3.x; acc.y += xv.w*w3.y; acc.z += xv.w*w3.z; acc.w += xv.w*w3.w;
    }
    *(float4*)(part + kc*C + o4*4) = acc;
  }
  __syncthreads();
}

// ---- encoder tiled GEMM stage (unchanged from round 2) ----
static __device__ void gemm_stage(const float* __restrict__ A, const float* __restrict__ W,
                                  const float* __restrict__ bias, const float* __restrict__ res,
                                  float* __restrict__ out, int R, int C, int K, int relu,
                                  float* sA) {
  const int t = threadIdx.x;
  const bool act = (t < 256);
  const int lane = t & 63, wv = (t >> 6) & 3;
  const int ntc = C >> 6;
  const int ntiles = (R >> 5) * ntc;
  for (int tile = blockIdx.x; tile < ntiles; tile += gridDim.x) {
    const int tr = tile / ntc, tc = tile - tr*ntc;
    const int r0 = tr << 5;
    const int c  = (tc << 6) + lane;
    float acc[8] = {0,0,0,0,0,0,0,0};
    for (int kc = 0; kc < K; kc += 256) {
      __syncthreads();
      if (act) {
#pragma unroll
        for (int u = 0; u < 8; u++) {
          int idx = u*256 + t;
          int rr = idx >> 6, cc = idx & 63;
          ((float4*)sA)[idx] = *(const float4*)(A + (r0+rr)*K + kc + cc*4);
        }
      }
      __syncthreads();
      if (act) {
        const float* wr = W + c*K + kc;
        for (int k = 0; k < 256; k += 4) {
          float4 w4 = *(const float4*)(wr + k);
#pragma unroll
          for (int r = 0; r < 8; r++) {
            float4 a4 = *(const float4*)(sA + (wv*8 + r)*256 + k);
            acc[r] += a4.x*w4.x; acc[r] += a4.y*w4.y; acc[r] += a4.z*w4.z; acc[r] += a4.w*w4.w;
          }
        }
      }
    }
    if (act) {
      float bb = bias ? bias[c] : 0.0f;
#pragma unroll
      for (int r = 0; r < 8; r++) {
        int row = r0 + wv*8 + r;
        float v = acc[r] + bb;
        if (relu) v = fmaxf(v, 0.0f);
        if (res)  v += res[row*C + c];
        out[row*C + c] = v;
      }
    }
  }
}

// ---- encoder LN stage ----
static __device__ void ln_stage(const float* in, const float* lw, const float* lb,
                                float* out, int R) {
  const int lane = threadIdx.x & 63;
  int gw = blockIdx.x*8 + (threadIdx.x >> 6);
  for (int row = gw; row < R; row += gridDim.x*8) {
    const float* ir = in + row*256;
    float x0 = ir[lane], x1 = ir[lane+64], x2 = ir[lane+128], x3 = ir[lane+192];
    float s = (x0 + x1) + (x2 + x3);
#pragma unroll
    for (int m = 1; m < 64; m <<= 1) s += __shfl_xor(s, m);
    float mean = s * 0.00390625f;
    float d0 = x0-mean, d1 = x1-mean, d2 = x2-mean, d3 = x3-mean;
    float q = (d0*d0 + d1*d1) + (d2*d2 + d3*d3);
#pragma unroll
    for (int m = 1; m < 64; m <<= 1) q += __shfl_xor(q, m);
    float rs = 1.0f / sqrtf(q * 0.00390625f + 1e-5f);
    float* orow = out + row*256;
    orow[lane]     = d0*rs*lw[lane]     + lb[lane];
    orow[lane+64]  = d1*rs*lw[lane+64]  + lb[lane+64];
    orow[lane+128] = d2*rs*lw[lane+128] + lb[lane+128];
    orow[lane+192] = d3*rs*lw[lane+192] + lb[lane+192];
  }
}

// ---- encoder attention core (unchanged; K rows in [p][d] layout) ----
static __device__ void attn_core(const float* qd, const float* kb, const float* vb,
                                 int krstride, int kstride, int nk,
                                 float* sc, float* red, float* ao) {
  const int t = threadIdx.x;
  const int r = t >> 5, p0 = t & 31;
  const bool act = (t < 256);
  if (act) {
#pragma unroll
    for (int pass = 0; pass < 2; pass++) {
      int p = pass*32 + p0;
      if (p < nk) {
        const float4* k4 = (const float4*)(kb + r*krstride + p*kstride);
        const float4* q4 = (const float4*)(qd + r*32);
        float a = 0.0f;
#pragma unroll
        for (int d4 = 0; d4 < 8; d4++) {
          float4 kv = k4[d4], qv = q4[d4];
          a += qv.x*kv.x; a += qv.y*kv.y; a += qv.z*kv.z; a += qv.w*kv.w;
        }
        sc[r*48 + p] = a * 0.17677669529663687f;
      }
    }
  }
  __syncthreads();
  if (t < 8) {
    float m = sc[t*48];
    for (int p = 1; p < nk; p++) m = fmaxf(m, sc[t*48 + p]);
    red[t] = m;
  }
  __syncthreads();
  if (act) {
#pragma unroll
    for (int pass = 0; pass < 2; pass++) {
      int p = pass*32 + p0;
      if (p < nk) sc[r*48 + p] = expf(sc[r*48 + p] - red[r]);
    }
  }
  __syncthreads();
  if (t < 8) {
    float s = 0.0f;
    for (int p = 0; p < nk; p++) s += sc[t*48 + p];
    red[8 + t] = s;
  }
  __syncthreads();
  if (act) {
#pragma unroll
    for (int pass = 0; pass < 2; pass++) {
      int p = pass*32 + p0;
      if (p < nk) sc[r*48 + p] = sc[r*48 + p] / red[8 + r];
    }
  }
  __syncthreads();
  if (act) {
    const int d2 = t & 31;
    const float* vr = vb + r*krstride + d2;
    float a = 0.0f;
    for (int p = 0; p < nk; p++) a += sc[r*48 + p] * vr[p*kstride];
    ao[r*32 + d2] = a;
  }
  __syncthreads();
}

static __device__ void enc_attn_stage(const float* QKV, float* AO, float* sm) {
  const int t = threadIdx.x;
  const bool act = (t < 256);
  float* qd  = sm;
  float* sc  = sm + 256;
  float* ao  = sm + 640;
  float* red = sm + 896;
  for (int pi = blockIdx.x; pi < 512; pi += gridDim.x) {
    int b = pi >> 3, h = pi & 7;
    const float* Qb = QKV + b*48*768 + h*32;
    const float* Kb = QKV + b*48*768 + 256 + h*32;
    const float* Vb = QKV + b*48*768 + 512 + h*32;
    for (int qg = 0; qg < 6; qg++) {
      if (act) { int r = t >> 5, d2 = t & 31; qd[r*32 + d2] = Qb[(qg*8 + r)*768 + d2]; }
      __syncthreads();
      attn_core(qd, Kb, Vb, 0, 768, 48, sc, red, ao);
      if (act) { int r = t >> 5, d2 = t & 31; AO[(b*48 + qg*8 + r)*256 + h*32 + d2] = ao[r*32 + d2]; }
      __syncthreads();
    }
  }
}

// ---- decode attention: K transposed [d4][p][4] (coalesced over p); V in [p][d] ----
static __device__ void attn_dec(const float* qd, const float* kt, const float* v,
                                int nk, float* sc, float* red, float* ao) {
  const int t = threadIdx.x;
  const int r = t >> 5, p0 = t & 31;
  const bool act = (t < 256);
  if (act) {
    const float4* q4 = (const float4*)(qd + r*32);
#pragma unroll
    for (int pass = 0; pass < 2; pass++) {
      int p = pass*32 + p0;
      if (p < nk) {
        const float* kb = kt + r*1536 + p*4;   // r = head; 8 d4-blocks of 192 floats
        float a = 0.0f;
#pragma unroll
        for (int j = 0; j < 8; j++) {
          float4 kv = *(const float4*)(kb + j*192);
          float4 qv = q4[j];
          a += qv.x*kv.x; a += qv.y*kv.y; a += qv.z*kv.z; a += qv.w*kv.w;
        }
        sc[r*48 + p] = a * 0.17677669529663687f;
      }
    }
  }
  __syncthreads();
  if (t < 8) {
    float m = sc[t*48];
    for (int p = 1; p < nk; p++) m = fmaxf(m, sc[t*48 + p]);
    red[t] = m;
  }
  __syncthreads();
  if (act) {
#pragma unroll
    for (int pass = 0; pass < 2; pass++) {
      int p = pass*32 + p0;
      if (p < nk) sc[r*48 + p] = expf(sc[r*48 + p] - red[r]);
    }
  }
  __syncthreads();
  if (t < 8) {
    float s = 0.0f;
    for (int p = 0; p < nk; p++) s += sc[t*48 + p];
    red[8 + t] = s;
  }
  __syncthreads();
  if (act) {
#pragma unroll
    for (int pass = 0; pass < 2; pass++) {
      int p = pass*32 + p0;
      if (p < nk) sc[r*48 + p] = sc[r*48 + p] / red[8 + r];
    }
  }
  __syncthreads();
  if (act) {
    const int d2 = t & 31;
    const float* vr = v + r*32 + d2;
    float a = 0.0f;
    for (int p = 0; p < nk; p++) a += sc[r*48 + p] * vr[p*256];
    ao[r*32 + d2] = a;
  }
  __syncthreads();
}

// ================= the single persistent kernel =================
__global__ void __launch_bounds__(512)
genrev3_kernel(GParams P) {
  __shared__ float sm[8448];
  float* ws = P.ws;
  const int wg = blockIdx.x;
  const int t  = threadIdx.x;

  // ---- E0: encoder embeddings + pe ----
  if (t < 256) {
    for (int rr = 0; rr < 12; rr++) {
      int row = wg*12 + rr;
      int b = row / 48, s = row % 48;
      int tok = (s < 32) ? P.xc[b*32 + s] : P.xct[b*16 + (s - 32)];
      ws[X_OFF + row*256 + t] = P.emb[(s*1024 + tok)*256 + t] + pe_val(s, t);
    }
  }
  gbar(&g_cntA, &g_genA, 256);

  // ---- encoder: 6 post-norm layers ----
  float* Xp = ws + X_OFF;
  for (int l = 0; l < 6; l++) {
    gemm_stage(Xp, P.ewqkv + l*768*256, P.ebqkv + l*768, nullptr, ws + QKV_OFF, 3072, 768, 256, 0, sm);
    gbar(&g_cntA, &g_genA, 256);
    enc_attn_stage(ws + QKV_OFF, ws + AO_OFF, sm);
    gbar(&g_cntA, &g_genA, 256);
    gemm_stage(ws + AO_OFF, P.ewo + l*256*256, P.ebo + l*256, Xp, ws + RES1_OFF, 3072, 256, 256, 0, sm);
    gbar(&g_cntA, &g_genA, 256);
    ln_stage(ws + RES1_OFF, P.elnw + (l*2 + 0)*256, P.elnb + (l*2 + 0)*256, ws + X1_OFF, 3072);
    gbar(&g_cntA, &g_genA, 256);
    gemm_stage(ws + X1_OFF, P.ew1 + l*1024*256, P.eb1 + l*1024, nullptr, ws + HB_OFF, 3072, 1024, 256, 1, sm);
    gbar(&g_cntA, &g_genA, 256);
    gemm_stage(ws + HB_OFF, P.ew2 + l*256*1024, P.eb2 + l*256, ws + X1_OFF, ws + RES2_OFF, 3072, 256, 1024, 0, sm);
    gbar(&g_cntA, &g_genA, 256);
    ln_stage(ws + RES2_OFF, P.elnw + (l*2 + 1)*256, P.elnb + (l*2 + 1)*256, Xp, 3072);
    gbar(&g_cntA, &g_genA, 256);
  }
  ln_stage(Xp, P.lnfw, P.lnfb, ws + MEM_OFF, 3072);
  gbar(&g_cntA, &g_genA, 256);
  // cross K (plain, temp at PCK) and cross V (final layout) for all 6 layers
  for (int l = 0; l < 6; l++) {
    gemm_stage(ws + MEM_OFF, P.cwqkv + (l*768 + 256)*256, P.cbqkv + l*768 + 256, nullptr,
               ws + PCK_OFF + l*786432, 3072, 256, 256, 0, sm);
    gemm_stage(ws + MEM_OFF, P.cwqkv + (l*768 + 512)*256, P.cbqkv + l*768 + 512, nullptr,
               ws + CV_OFF + l*786432, 3072, 256, 256, 0, sm);
  }
  gbar(&g_cntA, &g_genA, 256);

  // ---- transpose phase: decode weights -> [k][o]; plain cross-K -> [d4][p][4] ----
  {
    const int gt = wg*512 + t;
    const int GT = 256*512;
    for (int idx = gt; idx < 6*256*768; idx += GT) {
      int l = idx / 196608, r = idx - l*196608;
      int k = r / 768, o = r - k*768;
      ws[SWQKVT + idx] = P.swqkv[(l*768 + o)*256 + k];
    }
    for (int idx = gt; idx < 6*65536; idx += GT) {
      int l = idx >> 16, r = idx & 65535, k = r >> 8, o = r & 255;
      ws[SWOT + idx] = P.swo[(l*256 + o)*256 + k];
    }
    for (int idx = gt; idx < 6*65536; idx += GT) {
      int l = idx >> 16, r = idx & 65535, k = r >> 8, o = r & 255;
      ws[CWQT + idx] = P.cwqkv[(l*768 + o)*256 + k];
    }
    for (int idx = gt; idx < 6*65536; idx += GT) {
      int l = idx >> 16, r = idx & 65535, k = r >> 8, o = r & 255;
      ws[CWOT + idx] = P.cwo[(l*256 + o)*256 + k];
    }
    for (int idx = gt; idx < 6*262144; idx += GT) {
      int l = idx >> 18, r = idx & 262143, k = r >> 10, o = r & 1023;
      ws[DW1T + idx] = P.dw1[(l*1024 + o)*256 + k];
    }
    for (int idx = gt; idx < 6*262144; idx += GT) {
      int l = idx >> 18, r = idx & 262143, k = r >> 8, o = r & 255;
      ws[DW2T + idx] = P.dw2[(l*256 + o)*1024 + k];
    }
    // CKT[l][b][d4][p][c] from plain CK[l][b*48+p][d]
    for (int idx = gt; idx < 6*64*48*256; idx += GT) {
      int l = idx / 786432, r = idx - l*786432;
      int b = r / 12288, q = r - b*12288;
      int d4 = q / 192, s2 = q - d4*192;
      int p = s2 >> 2, c = s2 & 3;
      ws[CKT_OFF + idx] = ws[PCK_OFF + l*786432 + (b*48 + p)*256 + d4*4 + c];
    }
  }
  gbar(&g_cntA, &g_genA, 256);

  // ================= barrier-free per-row decode: WG b owns batch row b =================
  if (wg >= 64) return;
  const int b = wg;

  float* cur  = sm;           // 256
  float* qv   = sm + 256;     // 256
  float* av   = sm + 512;     // 256
  float* y1   = sm + 768;     // 256
  float* y2   = sm + 1024;    // 256
  float* hbf  = sm + 1280;    // 1024
  float* sc   = sm + 2304;    // 384
  float* red  = sm + 2688;    // 32
  float* y0   = sm + 2720;    // 256
  float* bvv  = sm + 2976;    // 256
  int*   bii  = (int*)(sm + 3232); // 256
  float* part = sm + 3488;    // 2048

  if (t < 256) y0[t] = P.sos[t] + pe_val(0, t);
  __syncthreads();

  for (int i = 0; i < 48; i++) {
    if (t < 256) cur[t] = y0[t];
    __syncthreads();
    for (int l = 0; l < 6; l++) {
      const int skt = SKT_OFF + l*786432 + b*12288;
      const int sv  = SV_OFF  + l*786432 + b*12288;
      const int ckt = CKT_OFF + l*786432 + b*12288;
      const int cv  = CV_OFF  + l*786432 + b*12288;
      // --- self QKV (transposed, coalesced, 2-way k-split) ---
      matvec_t<768,2,256>(ws + SWQKVT + l*196608, cur, part);
      for (int o = t; o < 768; o += 512) {
        float v = part[o] + part[768 + o] + P.sbqkv[l*768 + o];
        if (o < 256)      qv[o] = v;
        else if (o < 512) { int d = o - 256; ws[skt + (d>>2)*192 + i*4 + (d&3)] = v; }
        else              ws[sv + i*256 + (o - 512)] = v;
      }
      __syncthreads();
      attn_dec(qv, ws + skt, ws + sv, i + 1, sc, red, av);
      // --- self out-proj + residual + LN ---
      matvec_t<256,8,256>(ws + SWOT + l*65536, av, part);
      if (t < 256) {
        float s = part[t];
#pragma unroll
        for (int kc = 1; kc < 8; kc++) s += part[kc*256 + t];
        y1[t] = cur[t] + (s + P.sbo[l*256 + t]);
      }
      __syncthreads();
      if (t < 64) wave_ln_row(y1, P.dlnw + (l*3 + 0)*256, P.dlnb + (l*3 + 0)*256);
      __syncthreads();
      // --- cross q ---
      matvec_t<256,8,256>(ws + CWQT + l*65536, y1, part);
      if (t < 256) {
        float s = part[t];
#pragma unroll
        for (int kc = 1; kc < 8; kc++) s += part[kc*256 + t];
        qv[t] = s + P.cbqkv[l*768 + t];
      }
      __syncthreads();
      attn_dec(qv, ws + ckt, ws + cv, 48, sc, red, av);
      matvec_t<256,8,256>(ws + CWOT + l*65536, av, part);
      if (t < 256) {
        float s = part[t];
#pragma unroll
        for (int kc = 1; kc < 8; kc++) s += part[kc*256 + t];
        y2[t] = y1[t] + (s + P.cbo[l*256 + t]);
      }
      __syncthreads();
      if (t < 64) wave_ln_row(y2, P.dlnw + (l*3 + 1)*256, P.dlnb + (l*3 + 1)*256);
      __syncthreads();
      // --- FFN ---
      matvec_t<1024,2,256>(ws + DW1T + l*262144, y2, part);
      for (int o = t; o < 1024; o += 512)
        hbf[o] = fmaxf(part[o] + part[1024 + o] + P.db1[l*1024 + o], 0.0f);
      __syncthreads();
      matvec_t<256,8,1024>(ws + DW2T + l*262144, hbf, part);
      if (t < 256) {
        float s = part[t];
#pragma unroll
        for (int kc = 1; kc < 8; kc++) s += part[kc*256 + t];
        cur[t] = y2[t] + (s + P.db2[l*256 + t]);
      }
      __syncthreads();
      if (t < 64) wave_ln_row(cur, P.dlnw + (l*3 + 2)*256, P.dlnb + (l*3 + 2)*256);
      __syncthreads();
    }
    // --- final LN (lnf[1]) ---
    if (t < 64) wave_ln_row(cur, P.lnfw + 256, P.lnfb + 256);
    __syncthreads();
    // --- head: wave-cooperative rows (coalesced 1 KB/row, xor-tree reduce) ---
    {
      const int wv = t >> 6, lane = t & 63;
      const float4 x4 = *(const float4*)(cur + lane*4);
      for (int base = 0; base < 1024; base += 16) {
        int o = base + wv, o2 = o + 8;
        float4 wa = *(const float4*)(P.hw + (size_t)(i*1024 + o)*256 + lane*4);
        float4 wb = *(const float4*)(P.hw + (size_t)(i*1024 + o2)*256 + lane*4);
        float sa = wa.x*x4.x; sa += wa.y*x4.y; sa += wa.z*x4.z; sa += wa.w*x4.w;
        float sb = wb.x*x4.x; sb += wb.y*x4.y; sb += wb.z*x4.z; sb += wb.w*x4.w;
#pragma unroll
        for (int m = 1; m < 64; m <<= 1) { sa += __shfl_xor(sa, m); sb += __shfl_xor(sb, m); }
        if (lane == 0) {
          hbf[o]  = sa + P.hb[i*1024 + o];
          hbf[o2] = sb + P.hb[i*1024 + o2];
        }
      }
    }
    __syncthreads();
    for (int o = t; o < 1024; o += 512)
      P.out[3072 + i*65536 + b*1024 + o] = hbf[o];
    __syncthreads();
    // --- gumbel-argmax sampling ---
    unsigned k0, k1;
    step_key(i, k0, k1);
    if (t < 256) {
      float bestv = -INFINITY; int besti = 0;
#pragma unroll
      for (int e = 0; e < 4; e++) {
        int v = t*4 + e;
        unsigned bits = gumbel_bits(k0, k1, b, v);
        float f = __uint_as_float((bits >> 9) | 0x3f800000u);
        float u = fmaxf(f - 1.0f, 1.17549435e-38f);
        float g = -logf(-logf(u));
        float z = g + hbf[v] / 0.1f;
        if (z > bestv) { bestv = z; besti = v; }
      }
      bvv[t] = bestv; bii[t] = besti;
    }
    __syncthreads();
    for (int s = 128; s > 0; s >>= 1) {
      if (t < s) {
        float ov = bvv[t+s]; int oi = bii[t+s];
        if (ov > bvv[t] || (ov == bvv[t] && oi < bii[t])) { bvv[t] = ov; bii[t] = oi; }
      }
      __syncthreads();
    }
    const int ch = bii[0];
    if (t == 0) {
      if (i < 32) P.out[b*32 + i] = (float)ch;
      else        P.out[2048 + b*16 + (i - 32)] = (float)ch;
    }
    if (t < 256) y0[t] = P.emb[(i*1024 + ch)*256 + t] + pe_val(i + 1, t);
    __syncthreads();
  }
}

extern "C" void kernel_launch(void* const* d_in, const int* in_sizes, int n_in,
                              void* d_out, int out_size, void* d_ws, size_t ws_size,
                              hipStream_t stream) {
  (void)in_sizes; (void)n_in; (void)out_size; (void)ws_size;
  GParams p;
  p.xc    = (const int*)  d_in[0];
  p.xct   = (const int*)  d_in[1];
  p.sos   = (const float*)d_in[2];
  p.emb   = (const float*)d_in[3];
  p.hw    = (const float*)d_in[4];
  p.hb    = (const float*)d_in[5];
  p.ewqkv = (const float*)d_in[6];
  p.ebqkv = (const float*)d_in[7];
  p.ewo   = (const float*)d_in[8];
  p.ebo   = (const float*)d_in[9];
  p.ew1   = (const float*)d_in[10];
  p.eb1   = (const float*)d_in[11];
  p.ew2   = (const float*)d_in[12];
  p.eb2   = (const float*)d_in[13];
  p.elnw  = (const float*)d_in[14];
  p.elnb  = (const float*)d_in[15];
  p.swqkv = (const float*)d_in[16];
  p.sbqkv = (const float*)d_in[17];
  p.swo   = (const float*)d_in[18];
  p.sbo   = (const float*)d_in[19];
  p.cwqkv = (const float*)d_in[20];
  p.cbqkv = (const float*)d_in[21];
  p.cwo   = (const float*)d_in[22];
  p.cbo   = (const float*)d_in[23];
  p.dw1   = (const float*)d_in[24];
  p.db1   = (const float*)d_in[25];
  p.dw2   = (const float*)d_in[26];
  p.db2   = (const float*)d_in[27];
  p.dlnw  = (const float*)d_in[28];
  p.dlnb  = (const float*)d_in[29];
  p.lnfw  = (const float*)d_in[30];
  p.lnfb  = (const float*)d_in[31];
  p.out   = (float*)d_out;
  p.ws    = (float*)d_ws;
  hipLaunchKernelGGL(genrev3_kernel, dim3(256), dim3(512), 0, stream, p);
}